// Round 13
// baseline (146.707 us; speedup 1.0000x reference)
//
#include <hip/hip_runtime.h>
#include <hip/hip_bf16.h>

#define N_Z 16384
#define M_E 4096
#define DIM 256
#define NB5 1024                      // wise buckets (monotone map)
#define BMIN (-6.0f)
#define SCALE5 ((float)NB5 / 12.0f)

typedef __bf16 bf16x8 __attribute__((ext_vector_type(8)));
typedef float f32x4 __attribute__((ext_vector_type(4)));

__device__ __forceinline__ unsigned short f2bf(float f) {
  unsigned u = __float_as_uint(f);
  u = (u + 0x7FFFu + ((u >> 16) & 1u)) >> 16;
  return (unsigned short)u;
}

__device__ __forceinline__ void gl2lds16(const void* g, void* s) {
  __builtin_amdgcn_global_load_lds(
      (const __attribute__((address_space(1))) unsigned*)g,
      (__attribute__((address_space(3))) unsigned*)s, 16, 0, 0);
}

// order-preserving float<->uint map
__device__ __forceinline__ unsigned fmap(float f) {
  unsigned u = __float_as_uint(f);
  return (u & 0x80000000u) ? ~u : (u | 0x80000000u);
}
__device__ __forceinline__ float funmap(unsigned u) {
  return __uint_as_float((u & 0x80000000u) ? (u ^ 0x80000000u) : ~u);
}
// MONOTONE bucket map (v<w => bucket(v)<=bucket(w)); exactness needs only monotonicity
__device__ __forceinline__ int bucket5(float v) {
  int b = (int)((v - BMIN) * SCALE5);
  return min(max(b, 0), NB5 - 1);
}

// ---------------- prep2: z AND e -> bf16 + transpose + row sq-norm; block 0 inits ----------------
__global__ __launch_bounds__(256) void prep2_kernel(
    const float* __restrict__ z, const float* __restrict__ e,
    float* __restrict__ zT, float* __restrict__ eT,
    unsigned short* __restrict__ zb, unsigned short* __restrict__ eb,
    float* __restrict__ z2, float* __restrict__ e2,
    unsigned* __restrict__ d2min, float* __restrict__ wise_part,
    unsigned* __restrict__ wfin) {
  __shared__ float tile[32][33];
  int rblk = blockIdx.x * 32;
  int tx = threadIdx.x, ty = threadIdx.y;
  int lt = ty * 32 + tx;
  if (blockIdx.x == 0) {  // init side-jobs (consumed only by later kernels)
    for (int i = lt; i < M_E; i += 256) d2min[i] = 0x7F800000u;
    if (lt < 64) wise_part[lt] = 0.0f;
    if (lt == 0) *wfin = 0u;
  }
  const float* in;
  float* outT;
  unsigned short* outB;
  float* rsum;
  int R, r0;
  if (rblk < N_Z) {
    in = z; outT = zT; outB = zb; rsum = z2; R = N_Z; r0 = rblk;
  } else {
    in = e; outT = eT; outB = eb; rsum = e2; R = M_E; r0 = rblk - N_Z;
  }
  float acc[4] = {0.f, 0.f, 0.f, 0.f};
#pragma unroll 1
  for (int cc = 0; cc < DIM; cc += 32) {
#pragma unroll
    for (int i = 0; i < 4; ++i) {
      int rr = ty + 8 * i;
      float v = in[(size_t)(r0 + rr) * DIM + cc + tx];
      tile[rr][tx] = v;
      outB[(size_t)(r0 + rr) * DIM + cc + tx] = f2bf(v);
      acc[i] += v * v;
    }
    __syncthreads();
#pragma unroll
    for (int i = 0; i < 4; ++i)
      outT[(size_t)(cc + ty + 8 * i) * R + r0 + tx] = tile[tx][ty + 8 * i];
    __syncthreads();
  }
#pragma unroll
  for (int i = 0; i < 4; ++i) {
    float s = acc[i];
#pragma unroll
    for (int o = 1; o < 32; o <<= 1) s += __shfl_xor(s, o);  // xor<32: stays in row group
    if (tx == 0) rsum[r0 + ty + 8 * i] = s;
  }
}

// ---------------- fused bf16 GEMM (z . e^T) + min over n, per m — 256x256 tile ----------------
// K=256 makes this staging-BW-bound: 256^2 halves L2 staging traffic vs 128^2
// (A re-read x16 not x32, B x64 not x128) and 4x MFMA per barrier.
// 512 thr, 8 waves (2 N-halves x 4 M-quarters), acc[8][4], BK=64 + XOR swizzle.
__global__ __launch_bounds__(512) void gemm_min2_kernel(
    const unsigned short* __restrict__ zb, const unsigned short* __restrict__ eb,
    const float* __restrict__ z2, const float* __restrict__ e2,
    unsigned* __restrict__ d2min) {
  __shared__ __align__(16) unsigned short lA[256 * 64];  // z tile (N rows)
  __shared__ __align__(16) unsigned short lB[256 * 64];  // e tile (M rows)

  const int t = threadIdx.x;
  const int w = t >> 6;
  const int l = t & 63;
  const int wr = w >> 2;      // 0..1 : z-half (128 rows)
  const int wc = w & 3;       // 0..3 : e-quarter (64 cols)
  int flat = blockIdx.y * 16 + blockIdx.x;            // 1024 blocks (%8==0)
  int nf = (flat >> 3) + (flat & 7) * 128;            // bijective XCD swizzle
  const int tileM = (nf & 15) * 256;
  const int tileN = (nf >> 4) * 256;
  const int l15 = l & 15;
  const int kgr = l >> 4;

  f32x4 acc[8][4];
#pragma unroll
  for (int i = 0; i < 8; ++i)
#pragma unroll
    for (int j = 0; j < 4; ++j) acc[i][j] = (f32x4){0.f, 0.f, 0.f, 0.f};

#pragma unroll 1
  for (int k0 = 0; k0 < DIM; k0 += 64) {
    // stage 32KB per matrix: 2048 chunks of 16B, 4 per thread
#pragma unroll
    for (int i = 0; i < 4; ++i) {
      int c = i * 512 + t;
      int row = c >> 3;           // 0..255
      int kc = c & 7;
      int kcs = kc ^ (row & 7);   // pre-swizzled global source
      int ldsbase = (i * 512 + (t & ~63)) * 8;  // wave-uniform, elements
      gl2lds16(zb + (size_t)(tileN + row) * DIM + (k0 + kcs * 8), &lA[ldsbase]);
      gl2lds16(eb + (size_t)(tileM + row) * DIM + (k0 + kcs * 8), &lB[ldsbase]);
    }
    __syncthreads();

#pragma unroll
    for (int kk = 0; kk < 2; ++kk) {
      bf16x8 a[8], b[4];
      const int kcr = kk * 4 + kgr;
#pragma unroll
      for (int mi = 0; mi < 8; ++mi) {
        int row = wr * 128 + mi * 16 + l15;
        a[mi] = *(const bf16x8*)&lA[row * 64 + ((kcr ^ (row & 7)) * 8)];
      }
#pragma unroll
      for (int ni = 0; ni < 4; ++ni) {
        int row = wc * 64 + ni * 16 + l15;
        b[ni] = *(const bf16x8*)&lB[row * 64 + ((kcr ^ (row & 7)) * 8)];
      }
#pragma unroll
      for (int mi = 0; mi < 8; ++mi)
#pragma unroll
        for (int ni = 0; ni < 4; ++ni)
          acc[mi][ni] = __builtin_amdgcn_mfma_f32_16x16x32_bf16(a[mi], b[ni], acc[mi][ni], 0, 0, 0);
    }
    __syncthreads();
  }

  float* z2s = (float*)lA;
  if (t < 256) z2s[t] = z2[tileN + t];
  __syncthreads();

#pragma unroll
  for (int ni = 0; ni < 4; ++ni) {
    float v = 3.4e38f;
#pragma unroll
    for (int mi = 0; mi < 8; ++mi)
#pragma unroll
      for (int r = 0; r < 4; ++r) {
        int rloc = wr * 128 + mi * 16 + kgr * 4 + r;  // C/D: col=l15(e), row(z)
        v = fminf(v, z2s[rloc] - 2.0f * acc[mi][ni][r]);
      }
    v = fminf(v, __shfl_xor(v, 16));
    v = fminf(v, __shfl_xor(v, 32));
    if (l < 16) {
      int m = tileM + wc * 64 + ni * 16 + l;
      float d2 = v + e2[m];
      atomicMin(&d2min[m], __float_as_uint(d2));
    }
  }
}

// ---------------- wise8 (+ fused final reduce via completion counter) ----------------
__global__ __launch_bounds__(1024) void wise8_kernel(
    const float* __restrict__ zT, const float* __restrict__ eT,
    float* __restrict__ wise_part, const unsigned* __restrict__ d2min,
    unsigned* __restrict__ wfin, float* __restrict__ out) {
  extern __shared__ __align__(16) char smem[];
  float* zs = (float*)smem;                        // 16384 f (64K)
  unsigned* zoff = (unsigned*)(smem + 65536);      // 1024 u
  unsigned* pmax = zoff + NB5;                     // 1024 u
  unsigned* psminN = pmax + NB5;                   // 1024 u
  float* esorted = zs;                             // alias zs[0:4096] (phase E only)
  unsigned* eoff = zoff;                           // alias (phase E only)
  __shared__ unsigned scr[16];

  const int d = blockIdx.x, t = threadIdx.x;
  const int lane = t & 63, wid = t >> 6;

  // ---------- phase E: counting-sort e values ----------
  eoff[t] = 0u;
  __syncthreads();
  const float* ec = eT + (size_t)d * M_E;
  float ev4[4];
  int ebk[4];
#pragma unroll
  for (int i = 0; i < 4; ++i) {
    ev4[i] = ec[i * 1024 + t];
    ebk[i] = bucket5(ev4[i]);
    atomicAdd(&eoff[ebk[i]], 1u);
  }
  __syncthreads();
  {  // exclusive sum scan on eoff
    unsigned c = eoff[t];
    unsigned incl = c;
#pragma unroll
    for (int o = 1; o < 64; o <<= 1) {
      unsigned v = __shfl_up(incl, o);
      if (lane >= o) incl += v;
    }
    if (lane == 63) scr[wid] = incl;
    __syncthreads();
    if (t == 0) {
      unsigned run = 0;
#pragma unroll
      for (int i = 0; i < 16; ++i) { unsigned v = scr[i]; scr[i] = run; run += v; }
    }
    __syncthreads();
    unsigned excl = scr[wid] + incl - c;
    __syncthreads();
    eoff[t] = excl;
  }
  __syncthreads();
#pragma unroll
  for (int i = 0; i < 4; ++i) {
    unsigned pos = atomicAdd(&eoff[ebk[i]], 1u);
    esorted[pos] = ev4[i];
  }
  __syncthreads();
  float eq[4];
#pragma unroll
  for (int q = 0; q < 4; ++q) eq[q] = esorted[q * 1024 + t];  // sorted-slot order
  __syncthreads();

  // ---------- phase Z: build bucket-ordered z + tables ----------
  zoff[t] = 0u;
  __syncthreads();

  float zv[16];
  int zbk[16];
  const float4* p = (const float4*)(zT + (size_t)d * N_Z);
#pragma unroll
  for (int i = 0; i < 4; ++i) {
    float4 v = p[i * 1024 + t];
    zv[4 * i + 0] = v.x; zv[4 * i + 1] = v.y; zv[4 * i + 2] = v.z; zv[4 * i + 3] = v.w;
  }
#pragma unroll
  for (int i = 0; i < 16; ++i) {
    zbk[i] = bucket5(zv[i]);
    atomicAdd(&zoff[zbk[i]], 1u);
  }
  __syncthreads();

  {  // exclusive sum scan on zoff
    unsigned c = zoff[t];
    unsigned incl = c;
#pragma unroll
    for (int o = 1; o < 64; o <<= 1) {
      unsigned v = __shfl_up(incl, o);
      if (lane >= o) incl += v;
    }
    if (lane == 63) scr[wid] = incl;
    __syncthreads();
    if (t == 0) {
      unsigned run = 0;
#pragma unroll
      for (int i = 0; i < 16; ++i) { unsigned v = scr[i]; scr[i] = run; run += v; }
    }
    __syncthreads();
    unsigned excl = scr[wid] + incl - c;
    __syncthreads();
    zoff[t] = excl;
  }
  __syncthreads();

#pragma unroll
  for (int i = 0; i < 16; ++i) {
    unsigned pos = atomicAdd(&zoff[zbk[i]], 1u);
    zs[pos] = zv[i];
  }
  __syncthreads();

  // per-bucket min/max from exact slice scan (no over-scan in table build)
  {
    unsigned s0 = t ? zoff[t - 1] : 0u;
    unsigned s1 = zoff[t];
    unsigned mxU = 0u, mnN = 0u;
    for (unsigned j = s0; j < s1; ++j) {
      unsigned u = fmap(zs[j]);
      mxU = max(mxU, u);
      mnN = max(mnN, ~u);
    }
    pmax[t] = mxU;
    psminN[t] = mnN;
  }
  __syncthreads();

  // inclusive prefix-MAX scan on pmax (forward)
  {
    unsigned s = pmax[t];
    unsigned incl = s;
#pragma unroll
    for (int o = 1; o < 64; o <<= 1) {
      unsigned v = __shfl_up(incl, o);
      if (lane >= o) incl = max(incl, v);
    }
    __syncthreads();
    if (lane == 63) scr[wid] = incl;
    __syncthreads();
    if (t == 0) {
      unsigned run = 0;
#pragma unroll
      for (int i = 0; i < 16; ++i) { unsigned v = scr[i]; scr[i] = run; run = max(run, v); }
    }
    __syncthreads();
    pmax[t] = max(scr[wid], incl);
  }
  // inclusive suffix-MIN scan via prefix-max on ~fmap space, reversed index
  {
    int tr = NB5 - 1 - t;
    unsigned s = psminN[tr];
    unsigned incl = s;
#pragma unroll
    for (int o = 1; o < 64; o <<= 1) {
      unsigned v = __shfl_up(incl, o);
      if (lane >= o) incl = max(incl, v);
    }
    __syncthreads();
    if (lane == 63) scr[wid] = incl;
    __syncthreads();
    if (t == 0) {
      unsigned run = 0;
#pragma unroll
      for (int i = 0; i < 16; ++i) { unsigned v = scr[i]; scr[i] = run; run = max(run, v); }
    }
    __syncthreads();
    psminN[tr] = max(scr[wid], incl);
  }
  __syncthreads();

  // ---------- queries from regs: float4 over-scan + 2 table lookups ----------
  float accq = 0.0f;
#pragma unroll 1
  for (int q = 0; q < 4; ++q) {
    float ev = eq[q];
    int b0 = bucket5(ev);
    unsigned s0 = b0 ? zoff[b0 - 1] : 0u;
    unsigned s1 = zoff[b0];
    float best2 = 3.4e38f;
    if (b0 > 0) {
      unsigned u = pmax[b0 - 1];
      if (u) { float dd = funmap(u) - ev; best2 = dd * dd; }
    }
    if (b0 < NB5 - 1) {
      unsigned u = psminN[b0 + 1];
      if (u) { float dd = funmap(~u) - ev; best2 = fminf(best2, dd * dd); }
    }
    for (unsigned j = s0 & ~3u; j < s1; j += 4) {
      float4 zz = *(const float4*)&zs[j];
      float d0 = zz.x - ev, d1 = zz.y - ev;
      float d2 = zz.z - ev, d3 = zz.w - ev;
      best2 = fminf(best2, fminf(fminf(d0 * d0, d1 * d1), fminf(d2 * d2, d3 * d3)));
    }
    accq += best2;
  }

#pragma unroll
  for (int o = 32; o; o >>= 1) accq += __shfl_down(accq, o);
  __syncthreads();
  if (lane == 0) scr[wid] = __float_as_uint(accq);
  __syncthreads();

  // ---------- fused final: last-finishing block reduces everything ----------
  __shared__ unsigned amLast;
  if (t == 0) {
    float ssum = 0.0f;
#pragma unroll
    for (int i = 0; i < 16; ++i) ssum += __uint_as_float(scr[i]);
    atomicAdd(&wise_part[d & 63], ssum);
    __threadfence();
    amLast = (atomicAdd(wfin, 1u) == (unsigned)(DIM - 1)) ? 1u : 0u;
  }
  __syncthreads();
  if (amLast) {
    __threadfence();
    float s = 0.0f;
    for (int m = t; m < M_E; m += 1024) s += __uint_as_float(d2min[m]);
#pragma unroll
    for (int o = 32; o; o >>= 1) s += __shfl_down(s, o);
    __syncthreads();
    if (lane == 0) scr[wid] = __float_as_uint(s);
    __syncthreads();
    if (t == 0) {
      float tot = 0.0f;
#pragma unroll
      for (int i = 0; i < 16; ++i) tot += __uint_as_float(scr[i]);
      out[0] = tot / (float)M_E;
      float wsum = 0.0f;
      for (int i = 0; i < 64; ++i) wsum += wise_part[i];
      out[1] = wsum / ((float)M_E * (float)DIM);
    }
  }
}

extern "C" void kernel_launch(void* const* d_in, const int* in_sizes, int n_in,
                              void* d_out, int out_size, void* d_ws, size_t ws_size,
                              hipStream_t stream) {
  const float* z = (const float*)d_in[0];
  const float* e = (const float*)d_in[1];
  float* out = (float*)d_out;

  char* ws = (char*)d_ws;
  unsigned short* zb = (unsigned short*)ws;                 // 8 MiB
  unsigned short* eb = (unsigned short*)(ws + 8388608);     // 2 MiB
  float* z2 = (float*)(ws + 10485760);                      // 64 KiB
  float* e2 = (float*)(ws + 10551296);                      // 16 KiB
  unsigned* d2min = (unsigned*)(ws + 10567680);             // 16 KiB
  float* wise_part = (float*)(ws + 10584064);               // 256 B
  unsigned* wfin = (unsigned*)(ws + 10584320);              // 4 B
  float* zT = (float*)(ws + 11534336);                      // 16 MiB
  float* eT = (float*)(ws + 28311552);                      // 4 MiB -> 32505856

  const size_t LDS_WISE = 65536 + 3 * NB5 * 4;              // 77824 B -> 2 blocks/CU
  static int attr_done = 0;
  if (!attr_done) {
    (void)hipFuncSetAttribute((const void*)wise8_kernel,
                              hipFuncAttributeMaxDynamicSharedMemorySize, (int)LDS_WISE);
    attr_done = 1;
  }

  prep2_kernel<<<(N_Z + M_E) / 32, dim3(32, 8), 0, stream>>>(z, e, zT, eT, zb, eb, z2, e2,
                                                             d2min, wise_part, wfin);
  gemm_min2_kernel<<<dim3(16, 64), 512, 0, stream>>>(zb, eb, z2, e2, d2min);
  wise8_kernel<<<DIM, 1024, LDS_WISE, stream>>>(zT, eT, wise_part, d2min, wfin, out);
}